// Round 8
// baseline (8416.168 us; speedup 1.0000x reference)
//
#include <hip/hip_runtime.h>

typedef float f32x4 __attribute__((ext_vector_type(4)));
typedef __bf16 bf16x8 __attribute__((ext_vector_type(8)));
typedef unsigned short u16;

#define NB 256
#define TT 64
#define AD 32
#define OUTC 4864
#define OUTT ((size_t)63 * OUTC)

__device__ __forceinline__ u16 f2bf(float f) {
    unsigned u = __float_as_uint(f);
    u += 0x7FFFu + ((u >> 16) & 1u);
    return (u16)(u >> 16);
}
__device__ __forceinline__ float sigm(float x) { return 1.f / (1.f + expf(-x)); }
__device__ __forceinline__ float splus(float x) { return x > 15.f ? x : log1pf(expf(x)); }
__device__ __forceinline__ float eluf(float x) { return x > 0.f ? x : (expf(x) - 1.f); }
__device__ __forceinline__ int swz(int row, int cb) { return row * 128 + (cb ^ ((row & 7) << 4)); }

// -------- generic NT-tile 64x64 MFMA GEMM (R1/R3-proven, BK=64, depth-1) --------
// C[m][n0 + j*nstr + c] = sum_k A[m][k] * Bt[n][k]
template <int NT, class FA, class FE>
__device__ __forceinline__ void gemmN(char* As, FA fa, const u16* __restrict__ Bt,
                                      int ldb, int n0, int nstr, int K, int m0, FE fe) {
    char* Bs = As + 8192;
    const int tid = threadIdx.x;
    const int lane = tid & 63;
    const int w = tid >> 6;
    const int wr = (w >> 1) * 32, wc = (w & 1) * 32;
    f32x4 acc[NT][4];
    f32x4 zf = {0.f, 0.f, 0.f, 0.f};
#pragma unroll
    for (int j = 0; j < NT; j++)
#pragma unroll
        for (int q = 0; q < 4; q++) acc[j][q] = zf;
    const int r0 = tid >> 3;
    const int ke = (tid & 7) * 8;
    const int cb = (tid & 7) * 16;
    uint4 av0 = fa(m0 + r0, ke);
    uint4 av1 = fa(m0 + r0 + 32, ke);
    uint4 bv[NT][2];
#pragma unroll
    for (int j = 0; j < NT; j++) {
        bv[j][0] = *(const uint4*)(Bt + (size_t)(n0 + j * nstr + r0) * ldb + ke);
        bv[j][1] = *(const uint4*)(Bt + (size_t)(n0 + j * nstr + r0 + 32) * ldb + ke);
    }
    for (int k0 = 0; k0 < K; k0 += 64) {
        __syncthreads();
        *(uint4*)(As + swz(r0, cb)) = av0;
        *(uint4*)(As + swz(r0 + 32, cb)) = av1;
#pragma unroll
        for (int j = 0; j < NT; j++) {
            char* B = Bs + j * 8192;
            *(uint4*)(B + swz(r0, cb)) = bv[j][0];
            *(uint4*)(B + swz(r0 + 32, cb)) = bv[j][1];
        }
        __syncthreads();
        if (k0 + 64 < K) {
            int k1 = k0 + 64 + ke;
            av0 = fa(m0 + r0, k1);
            av1 = fa(m0 + r0 + 32, k1);
#pragma unroll
            for (int j = 0; j < NT; j++) {
                bv[j][0] = *(const uint4*)(Bt + (size_t)(n0 + j * nstr + r0) * ldb + k1);
                bv[j][1] = *(const uint4*)(Bt + (size_t)(n0 + j * nstr + r0 + 32) * ldb + k1);
            }
        }
#pragma unroll
        for (int kk = 0; kk < 64; kk += 32) {
            const int fcb = kk * 2 + (lane >> 4) * 16;
            bf16x8 a0 = *(const bf16x8*)(As + swz(wr + (lane & 15), fcb));
            bf16x8 a1 = *(const bf16x8*)(As + swz(wr + 16 + (lane & 15), fcb));
#pragma unroll
            for (int j = 0; j < NT; j++) {
                char* B = Bs + j * 8192;
                bf16x8 b0 = *(const bf16x8*)(B + swz(wc + (lane & 15), fcb));
                bf16x8 b1 = *(const bf16x8*)(B + swz(wc + 16 + (lane & 15), fcb));
                acc[j][0] = __builtin_amdgcn_mfma_f32_16x16x32_bf16(a0, b0, acc[j][0], 0, 0, 0);
                acc[j][1] = __builtin_amdgcn_mfma_f32_16x16x32_bf16(a0, b1, acc[j][1], 0, 0, 0);
                acc[j][2] = __builtin_amdgcn_mfma_f32_16x16x32_bf16(a1, b0, acc[j][2], 0, 0, 0);
                acc[j][3] = __builtin_amdgcn_mfma_f32_16x16x32_bf16(a1, b1, acc[j][3], 0, 0, 0);
            }
        }
    }
    const int er = (lane >> 4) * 4, ec = lane & 15;
#pragma unroll
    for (int q = 0; q < 4; q++) {
        int rr = m0 + wr + (q >> 1) * 16 + er;
        int cc = n0 + wc + (q & 1) * 16 + ec;
#pragma unroll
        for (int r = 0; r < 4; r++) {
            float vals[NT];
#pragma unroll
            for (int j = 0; j < NT; j++) vals[j] = acc[j][q][r];
            fe(rr + r, cc, vals);
        }
    }
}

// ---------------- weight prep (R1 verbatim) ----------------
__global__ void __launch_bounds__(256) k_cast(const float* __restrict__ in,
                                              u16* __restrict__ out, int n) {
    int i = blockIdx.x * 256 + threadIdx.x;
    if (i < n) out[i] = f2bf(in[i]);
}

__global__ void __launch_bounds__(256) k_transpose(const float* __restrict__ in,
                                                   u16* __restrict__ out,
                                                   int R, int C, int Rpad, int total) {
    int i = blockIdx.x * 256 + threadIdx.x;
    if (i >= total) return;
    int r = i % Rpad;
    int bc = i / Rpad;
    int c = bc % C;
    int bb = bc / C;
    out[i] = (r < R) ? f2bf(in[((size_t)bb * R + r) * C + c]) : (u16)0;
}

// ---------------- init (R1 verbatim) ----------------
__global__ void __launch_bounds__(256) k_prep0(const float* __restrict__ init_deter,
                                               const float* __restrict__ init_stoch,
                                               const float* __restrict__ action,
                                               const float* __restrict__ nonterms,
                                               float* __restrict__ deter,
                                               u16* __restrict__ h_nt,
                                               u16* __restrict__ x_embed) {
    int idx = blockIdx.x * 256 + threadIdx.x;
    int b = idx >> 10, d = idx & 1023;
    float nt0 = nonterms[b * TT + 0];
    float dv = init_deter[idx];
    deter[idx] = dv;
    h_nt[idx] = f2bf(dv * nt0);
    if (d < 256) {
        x_embed[b * 320 + d] = f2bf(init_stoch[b * 256 + d] * nt0);
    } else if (d < 320) {
        int c = d - 256;
        x_embed[b * 320 + d] = (c < AD) ? f2bf(action[(size_t)b * TT * AD + c] * nt0) : (u16)0;
    }
}

// ---------------- S3: GRU (R1 verbatim + h_nt write) ----------------
__global__ void __launch_bounds__(256) k_gru(const float* __restrict__ gi,
                                             const float* __restrict__ gh,
                                             float* __restrict__ deter,
                                             const float* __restrict__ nonterms, int t,
                                             u16* __restrict__ deter_b,
                                             u16* __restrict__ h_nt,
                                             float* __restrict__ out) {
    int idx = blockIdx.x * 256 + threadIdx.x;
    int b = idx >> 10, d = idx & 1023;
    float nt = nonterms[b * TT + t];
    float h = deter[idx] * nt;
    size_t gb = (size_t)b * 3072;
    float r = sigm(gi[gb + d] + gh[gb + d]);
    float z = sigm(gi[gb + 1024 + d] + gh[gb + 1024 + d]);
    float n = tanhf(gi[gb + 2048 + d] + r * gh[gb + 2048 + d]);
    float dn = (1.f - z) * n + z * h;
    deter[idx] = dn;
    deter_b[idx] = f2bf(dn);
    h_nt[idx] = f2bf(dn * nonterms[b * TT + t + 1]);
    float* ob = out + (size_t)b * OUTT + (size_t)t * OUTC;
    ob[768 + d] = dn;
    ob[2560 + d] = dn;
}

// ---------------- S1: sa (R1 verbatim) ----------------
__global__ void __launch_bounds__(256) k_gemm_sa(const u16* __restrict__ xe,
                                                 const u16* __restrict__ Wt,
                                                 const float* __restrict__ bias,
                                                 u16* __restrict__ sa) {
    __shared__ char sm[16384];
    int m0 = blockIdx.y * 64, n0 = blockIdx.x * 64;
    auto fa = [&](int r, int k) { return *(const uint4*)(xe + r * 320 + k); };
    auto fe = [&](int r, int n, const float* v) {
        sa[r * 1024 + n] = f2bf(eluf(v[0] + bias[n]));
    };
    gemmN<1>(sm, fa, Wt, 320, n0, 0, 320, m0, fe);
}

// ---------------- S2: gi / gh / ens (R1 verbatim) ----------------
__global__ void __launch_bounds__(256) k_gemm_big(const u16* __restrict__ sa,
                                                  const u16* __restrict__ hnt,
                                                  const u16* __restrict__ Wih,
                                                  const u16* __restrict__ Whh,
                                                  const u16* __restrict__ Wens,
                                                  const float* __restrict__ bih,
                                                  const float* __restrict__ bhh,
                                                  const float* __restrict__ bens,
                                                  float* __restrict__ gi,
                                                  float* __restrict__ gh,
                                                  float* __restrict__ dout, int t) {
    __shared__ char sm[16384];
    int z = blockIdx.z;
    int m0 = blockIdx.y * 64, n0 = blockIdx.x * 64;
    if (z == 2 && n0 >= 1280) return;
    const u16* Ap = (z == 1) ? hnt : sa;
    auto fa = [&](int r, int k) { return *(const uint4*)(Ap + r * 1024 + k); };
    if (z == 0) {
        auto fe = [&](int r, int n, const float* v) { gi[(size_t)r * 3072 + n] = v[0] + bih[n]; };
        gemmN<1>(sm, fa, Wih, 1024, n0, 0, 1024, m0, fe);
    } else if (z == 1) {
        auto fe = [&](int r, int n, const float* v) { gh[(size_t)r * 3072 + n] = v[0] + bhh[n]; };
        gemmN<1>(sm, fa, Whh, 1024, n0, 0, 1024, m0, fe);
    } else {
        float* op = dout + (size_t)t * OUTC + 3584;
        auto fe = [&](int r, int n, const float* v) { op[(size_t)r * OUTT + n] = v[0] + bens[n]; };
        gemmN<1>(sm, fa, Wens, 1024, n0, 0, 1024, m0, fe);
    }
}

// ---------------- S4: hp / hq (R1 verbatim, hq K=2048 with obs loader) ----------------
__global__ void __launch_bounds__(256) k_gemm_hpq(const u16* __restrict__ dtb,
                                                  const float* __restrict__ obs,
                                                  const u16* __restrict__ Wp1t,
                                                  const u16* __restrict__ Wq1t,
                                                  const float* __restrict__ bp1,
                                                  const float* __restrict__ bq1,
                                                  u16* __restrict__ hp,
                                                  u16* __restrict__ hq, int t) {
    __shared__ char sm[16384];
    int z = blockIdx.z;
    int m0 = blockIdx.y * 64, n0 = blockIdx.x * 64;
    if (z == 0) {
        auto fa = [&](int r, int k) { return *(const uint4*)(dtb + r * 1024 + k); };
        auto fe = [&](int r, int n, const float* v) {
            hp[r * 1024 + n] = f2bf(eluf(v[0] + bp1[n]));
        };
        gemmN<1>(sm, fa, Wp1t, 1024, n0, 0, 1024, m0, fe);
    } else {
        auto fa = [&](int r, int k) {
            if (k < 1024) return *(const uint4*)(dtb + r * 1024 + k);
            const float* q = obs + (size_t)r * (TT * 1024) + (size_t)t * 1024 + (k - 1024);
            float4 f0 = *(const float4*)q, f1 = *(const float4*)(q + 4);
            union { u16 u[8]; uint4 v; } x;
            x.u[0] = f2bf(f0.x); x.u[1] = f2bf(f0.y); x.u[2] = f2bf(f0.z); x.u[3] = f2bf(f0.w);
            x.u[4] = f2bf(f1.x); x.u[5] = f2bf(f1.y); x.u[6] = f2bf(f1.z); x.u[7] = f2bf(f1.w);
            return x.v;
        };
        auto fe = [&](int r, int n, const float* v) {
            hq[r * 1024 + n] = f2bf(eluf(v[0] + bq1[n]));
        };
        gemmN<1>(sm, fa, Wq1t, 2048, n0, 0, 2048, m0, fe);
    }
}

// ---------------- S5: p2/q2 GEMM + sampling epilogue (R3-validated pattern) ----------------
__global__ void __launch_bounds__(256) k_pq_dist(const u16* __restrict__ hp,
                                                 const u16* __restrict__ hq,
                                                 const u16* __restrict__ Wp2t,
                                                 const u16* __restrict__ Wq2t,
                                                 const float* __restrict__ bp2,
                                                 const float* __restrict__ bq2,
                                                 const float* __restrict__ noise_p,
                                                 const float* __restrict__ noise_q,
                                                 const float* __restrict__ nonterms,
                                                 const float* __restrict__ action,
                                                 float* __restrict__ out,
                                                 u16* __restrict__ x_embed, int t) {
    __shared__ char sm[24576];
    int bid = blockIdx.x;
    if (bid < 32) {
        bool isq = bid >= 16;
        int j = bid & 15;
        int m0 = (j >> 2) * 64, n0 = (j & 3) * 64;
        const u16* A = isq ? hq : hp;
        const u16* B = isq ? Wq2t : Wp2t;
        const float* b2 = isq ? bq2 : bp2;
        const float* noise = isq ? noise_q : noise_p;
        int obase = isq ? 1792 : 0;
        auto fa = [&](int r, int k) { return *(const uint4*)(A + r * 1024 + k); };
        auto fe = [&](int r, int s, const float* v) {
            float m = v[0] + b2[s];
            float sd = splus(v[1] + b2[s + 256]) + 0.1f;
            float eps = noise[(size_t)t * 65536 + r * 256 + s];
            float st = m + sd * eps;
            float* obp = out + (size_t)r * OUTT + (size_t)t * OUTC + obase;
            obp[s] = m;
            obp[256 + s] = sd;
            obp[512 + s] = st;
            if (isq) {
                float ntn = nonterms[r * TT + t + 1];
                x_embed[r * 320 + s] = f2bf(st * ntn);
            }
        };
        gemmN<2>(sm, fa, B, 1024, n0, 256, 1024, m0, fe);
    } else {
        for (int i = (bid - 32) * 256 + threadIdx.x; i < 16384; i += 1024) {
            int b = i >> 6, c = i & 63;
            float ntn = nonterms[b * TT + t + 1];
            u16 v = 0;
            if (c < AD) v = f2bf(action[(size_t)b * TT * AD + (size_t)(t + 1) * AD + c] * ntn);
            x_embed[b * 320 + 256 + c] = v;
        }
    }
}

// ---------------- host ----------------
extern "C" void kernel_launch(void* const* d_in, const int* in_sizes, int n_in,
                              void* d_out, int out_size, void* d_ws, size_t ws_size,
                              hipStream_t stream) {
    const float* obs = (const float*)d_in[1];
    const float* action = (const float*)d_in[2];
    const float* nonterms = (const float*)d_in[3];
    const float* init_deter = (const float*)d_in[4];
    const float* init_stoch = (const float*)d_in[5];
    const float* noise_p = (const float*)d_in[6];
    const float* noise_q = (const float*)d_in[7];
    const float* W_embed = (const float*)d_in[8];
    const float* b_embed = (const float*)d_in[9];
    const float* W_ens = (const float*)d_in[10];
    const float* b_ens = (const float*)d_in[11];
    const float* W_ih = (const float*)d_in[12];
    const float* W_hh = (const float*)d_in[13];
    const float* b_ih = (const float*)d_in[14];
    const float* b_hh = (const float*)d_in[15];
    const float* Wp1 = (const float*)d_in[16];
    const float* bp1 = (const float*)d_in[17];
    const float* Wp2 = (const float*)d_in[18];
    const float* bp2 = (const float*)d_in[19];
    const float* Wq1 = (const float*)d_in[20];
    const float* bq1 = (const float*)d_in[21];
    const float* Wq2 = (const float*)d_in[22];
    const float* bq2 = (const float*)d_in[23];
    float* out = (float*)d_out;

    char* ws = (char*)d_ws;
    size_t off = 0;
    auto alloc = [&](size_t bytes) {
        void* p = ws + off;
        off += (bytes + 255) & ~(size_t)255;
        return p;
    };
    u16* Wembed_t = (u16*)alloc((size_t)1024 * 320 * 2);
    u16* Wih_b = (u16*)alloc((size_t)3072 * 1024 * 2);
    u16* Whh_b = (u16*)alloc((size_t)3072 * 1024 * 2);
    u16* Wens_t = (u16*)alloc((size_t)1280 * 1024 * 2);
    u16* Wp1_t = (u16*)alloc((size_t)1024 * 1024 * 2);
    u16* Wp2_t = (u16*)alloc((size_t)512 * 1024 * 2);
    u16* Wq1_t = (u16*)alloc((size_t)1024 * 2048 * 2);
    u16* Wq2_t = (u16*)alloc((size_t)512 * 1024 * 2);
    u16* x_embed = (u16*)alloc((size_t)256 * 320 * 2);
    u16* h_nt = (u16*)alloc((size_t)256 * 1024 * 2);
    u16* sa = (u16*)alloc((size_t)256 * 1024 * 2);
    float* deter = (float*)alloc((size_t)256 * 1024 * 4);
    u16* deter_b = (u16*)alloc((size_t)256 * 1024 * 2);
    float* gi = (float*)alloc((size_t)256 * 3072 * 4);
    float* gh = (float*)alloc((size_t)256 * 3072 * 4);
    u16* hp = (u16*)alloc((size_t)256 * 1024 * 2);
    u16* hq = (u16*)alloc((size_t)256 * 1024 * 2);
    (void)ws_size; (void)in_sizes; (void)n_in; (void)out_size;

    // weights: cast / transpose to bf16 [N][K]  (R1 verbatim)
    {
        int tot = 1024 * 320;
        k_transpose<<<(tot + 255) / 256, 256, 0, stream>>>(W_embed, Wembed_t, 288, 1024, 320, tot);
        int nc = 3072 * 1024;
        k_cast<<<(nc + 255) / 256, 256, 0, stream>>>(W_ih, Wih_b, nc);
        k_cast<<<(nc + 255) / 256, 256, 0, stream>>>(W_hh, Whh_b, nc);
        tot = 5 * 256 * 1024;
        k_transpose<<<(tot + 255) / 256, 256, 0, stream>>>(W_ens, Wens_t, 1024, 256, 1024, tot);
        tot = 1024 * 1024;
        k_transpose<<<(tot + 255) / 256, 256, 0, stream>>>(Wp1, Wp1_t, 1024, 1024, 1024, tot);
        tot = 512 * 1024;
        k_transpose<<<(tot + 255) / 256, 256, 0, stream>>>(Wp2, Wp2_t, 1024, 512, 1024, tot);
        tot = 1024 * 2048;
        k_transpose<<<(tot + 255) / 256, 256, 0, stream>>>(Wq1, Wq1_t, 2048, 1024, 2048, tot);
        tot = 512 * 1024;
        k_transpose<<<(tot + 255) / 256, 256, 0, stream>>>(Wq2, Wq2_t, 1024, 512, 1024, tot);
    }

    k_prep0<<<1024, 256, 0, stream>>>(init_deter, init_stoch, action, nonterms,
                                      deter, h_nt, x_embed);

    for (int t = 0; t < 63; t++) {
        k_gemm_sa<<<dim3(16, 4), 256, 0, stream>>>(x_embed, Wembed_t, b_embed, sa);
        k_gemm_big<<<dim3(48, 4, 3), 256, 0, stream>>>(sa, h_nt, Wih_b, Whh_b, Wens_t,
                                                       b_ih, b_hh, b_ens, gi, gh, out, t);
        k_gru<<<1024, 256, 0, stream>>>(gi, gh, deter, nonterms, t, deter_b, h_nt, out);
        k_gemm_hpq<<<dim3(16, 4, 2), 256, 0, stream>>>(deter_b, obs, Wp1_t, Wq1_t,
                                                       bp1, bq1, hp, hq, t);
        k_pq_dist<<<36, 256, 0, stream>>>(hp, hq, Wp2_t, Wq2_t, bp2, bq2,
                                          noise_p, noise_q, nonterms, action,
                                          out, x_embed, t);
    }
}

// Round 9
// 4887.151 us; speedup vs baseline: 1.7221x; 1.7221x over previous
//

#include <hip/hip_runtime.h>

typedef float f32x4 __attribute__((ext_vector_type(4)));
typedef __bf16 bf16x8 __attribute__((ext_vector_type(8)));
typedef unsigned short u16;

#define NB 256           // batch
#define TT 64            // T
#define TM1 63
#define DD 1024
#define SS 256
#define EE 1024
#define AD 32
#define OUTC 4864        // 2*(3S+D)+K*S
#define OUTT ((size_t)TM1 * OUTC)

__device__ __forceinline__ u16 f2bf(float f) {
    unsigned u = __float_as_uint(f);
    u += 0x7FFFu + ((u >> 16) & 1u);
    return (u16)(u >> 16);
}
__device__ __forceinline__ float sigm(float x) { return 1.f / (1.f + expf(-x)); }
__device__ __forceinline__ float splus(float x) { return x > 15.f ? x : log1pf(expf(x)); }
__device__ __forceinline__ float eluf(float x) { return x > 0.f ? x : (expf(x) - 1.f); }
__device__ __forceinline__ int swz(int row, int cb) { return row * 128 + (cb ^ ((row & 7) << 4)); }

// ---------------- generic 64x64 MFMA GEMM tile ----------------
// C[m][n] = sum_k A[m][k] * Bt[n][k]   (A via loader fa, Bt bf16 [N][ldb])
template <class FA, class FE>
__device__ __forceinline__ void gemm_tile(char* As, char* Bs, FA fa,
                                          const u16* __restrict__ Bt, int ldb,
                                          int K, int m0, int n0, FE fe) {
    const int tid = threadIdx.x;
    const int lane = tid & 63;
    const int w = tid >> 6;
    const int wr = (w >> 1) * 32, wc = (w & 1) * 32;
    f32x4 acc00 = {}, acc01 = {}, acc10 = {}, acc11 = {};
    const int r0 = tid >> 3;        // 0..31
    const int ke = (tid & 7) * 8;   // k element offset within 64
    const int cb = (tid & 7) * 16;  // byte offset within 128B row

    for (int k0 = 0; k0 < K; k0 += 64) {
        uint4 av0 = fa(m0 + r0, k0 + ke);
        uint4 av1 = fa(m0 + r0 + 32, k0 + ke);
        uint4 bv0 = *(const uint4*)(Bt + (size_t)(n0 + r0) * ldb + k0 + ke);
        uint4 bv1 = *(const uint4*)(Bt + (size_t)(n0 + r0 + 32) * ldb + k0 + ke);
        __syncthreads();
        *(uint4*)(As + swz(r0, cb)) = av0;
        *(uint4*)(As + swz(r0 + 32, cb)) = av1;
        *(uint4*)(Bs + swz(r0, cb)) = bv0;
        *(uint4*)(Bs + swz(r0 + 32, cb)) = bv1;
        __syncthreads();
#pragma unroll
        for (int kk = 0; kk < 64; kk += 32) {
            const int fcb = kk * 2 + (lane >> 4) * 16;
            bf16x8 a0 = *(const bf16x8*)(As + swz(wr + (lane & 15), fcb));
            bf16x8 a1 = *(const bf16x8*)(As + swz(wr + 16 + (lane & 15), fcb));
            bf16x8 b0 = *(const bf16x8*)(Bs + swz(wc + (lane & 15), fcb));
            bf16x8 b1 = *(const bf16x8*)(Bs + swz(wc + 16 + (lane & 15), fcb));
            acc00 = __builtin_amdgcn_mfma_f32_16x16x32_bf16(a0, b0, acc00, 0, 0, 0);
            acc01 = __builtin_amdgcn_mfma_f32_16x16x32_bf16(a0, b1, acc01, 0, 0, 0);
            acc10 = __builtin_amdgcn_mfma_f32_16x16x32_bf16(a1, b0, acc10, 0, 0, 0);
            acc11 = __builtin_amdgcn_mfma_f32_16x16x32_bf16(a1, b1, acc11, 0, 0, 0);
        }
    }
    const int er = (lane >> 4) * 4, ec = lane & 15;
#pragma unroll
    for (int r = 0; r < 4; r++) {
        fe(m0 + wr + er + r, n0 + wc + ec, acc00[r]);
        fe(m0 + wr + er + r, n0 + wc + 16 + ec, acc01[r]);
        fe(m0 + wr + 16 + er + r, n0 + wc + ec, acc10[r]);
        fe(m0 + wr + 16 + er + r, n0 + wc + 16 + ec, acc11[r]);
    }
}

// ---------------- weight prep ----------------
__global__ void __launch_bounds__(256) k_cast(const float* __restrict__ in,
                                              u16* __restrict__ out, int n) {
    int i = blockIdx.x * 256 + threadIdx.x;
    if (i < n) out[i] = f2bf(in[i]);
}

// out[(b*C + c)*Rpad + r] = r < R ? in[b*R*C + r*C + c] : 0
__global__ void __launch_bounds__(256) k_transpose(const float* __restrict__ in,
                                                   u16* __restrict__ out,
                                                   int R, int C, int Rpad, int total) {
    int i = blockIdx.x * 256 + threadIdx.x;
    if (i >= total) return;
    int r = i % Rpad;
    int bc = i / Rpad;
    int c = bc % C;
    int bb = bc / C;
    out[i] = (r < R) ? f2bf(in[((size_t)bb * R + r) * C + c]) : (u16)0;
}

// ---------------- pointwise ----------------
__global__ void __launch_bounds__(256) k_prep0(const float* __restrict__ init_deter,
                                               const float* __restrict__ init_stoch,
                                               const float* __restrict__ action,
                                               const float* __restrict__ nonterms,
                                               float* __restrict__ deter,
                                               u16* __restrict__ h_nt,
                                               u16* __restrict__ x_embed) {
    int idx = blockIdx.x * 256 + threadIdx.x;  // 256*1024
    int b = idx >> 10, d = idx & 1023;
    float nt0 = nonterms[b * TT + 0];
    float dv = init_deter[idx];
    deter[idx] = dv;
    h_nt[idx] = f2bf(dv * nt0);
    if (d < 256) {
        x_embed[b * 320 + d] = f2bf(init_stoch[b * 256 + d] * nt0);
    } else if (d < 320) {
        int c = d - 256;
        x_embed[b * 320 + d] = (c < AD) ? f2bf(action[(size_t)b * TT * AD + c] * nt0) : (u16)0;
    }
}

__global__ void __launch_bounds__(256) k_gru(const float* __restrict__ gi,
                                             const float* __restrict__ gh,
                                             float* __restrict__ deter,
                                             const float* __restrict__ nonterms, int t,
                                             u16* __restrict__ deter_b,
                                             float* __restrict__ out) {
    int idx = blockIdx.x * 256 + threadIdx.x;
    int b = idx >> 10, d = idx & 1023;
    float nt = nonterms[b * TT + t];
    float h = deter[idx] * nt;
    size_t gb = (size_t)b * 3072;
    float r = sigm(gi[gb + d] + gh[gb + d]);
    float z = sigm(gi[gb + 1024 + d] + gh[gb + 1024 + d]);
    float n = tanhf(gi[gb + 2048 + d] + r * gh[gb + 2048 + d]);
    float dn = (1.f - z) * n + z * h;
    deter[idx] = dn;
    deter_b[idx] = f2bf(dn);
    float* ob = out + (size_t)b * OUTT + (size_t)t * OUTC;
    ob[768 + d] = dn;
    ob[2560 + d] = dn;
}

__global__ void __launch_bounds__(256) k_dist(const float* __restrict__ pout,
                                              const float* __restrict__ qout,
                                              const float* __restrict__ noise_p,
                                              const float* __restrict__ noise_q, int t,
                                              const float* __restrict__ deter,
                                              const float* __restrict__ action,
                                              const float* __restrict__ nonterms,
                                              float* __restrict__ out,
                                              u16* __restrict__ x_embed,
                                              u16* __restrict__ h_nt) {
    int idx = blockIdx.x * 256 + threadIdx.x;
    int b = idx >> 10, d = idx & 1023;
    float ntn = nonterms[b * TT + (t + 1)];
    h_nt[idx] = f2bf(deter[idx] * ntn);
    float* ob = out + (size_t)b * OUTT + (size_t)t * OUTC;
    if (d < 256) {
        int s = d;
        float pm = pout[b * 512 + s];
        float ps = splus(pout[b * 512 + 256 + s]) + 0.1f;
        float ep = noise_p[(size_t)t * (NB * SS) + b * SS + s];
        float pst = pm + ps * ep;
        ob[s] = pm;
        ob[256 + s] = ps;
        ob[512 + s] = pst;
        float qm = qout[b * 512 + s];
        float qs = splus(qout[b * 512 + 256 + s]) + 0.1f;
        float eq = noise_q[(size_t)t * (NB * SS) + b * SS + s];
        float qst = qm + qs * eq;
        ob[1792 + s] = qm;
        ob[2048 + s] = qs;
        ob[2304 + s] = qst;
        x_embed[b * 320 + s] = f2bf(qst * ntn);
    } else if (d < 320) {
        int c = d - 256;
        u16 v = 0;
        if (c < AD) v = f2bf(action[(size_t)b * TT * AD + (size_t)(t + 1) * AD + c] * ntn);
        x_embed[b * 320 + 256 + c] = v;
    }
}

// ---------------- GEMM kernels ----------------
__global__ void __launch_bounds__(256) k_gemm_sa(const u16* __restrict__ xe,
                                                 const u16* __restrict__ Wt,
                                                 const float* __restrict__ bias,
                                                 u16* __restrict__ sa) {
    __shared__ char As[8192];
    __shared__ char Bs[8192];
    int m0 = blockIdx.y * 64, n0 = blockIdx.x * 64;
    auto fa = [&](int r, int k) { return *(const uint4*)(xe + r * 320 + k); };
    auto fe = [&](int r, int n, float v) {
        v = eluf(v + bias[n]);
        sa[r * 1024 + n] = f2bf(v);
    };
    gemm_tile(As, Bs, fa, Wt, 320, 320, m0, n0, fe);
}

__global__ void __launch_bounds__(256) k_gemm_big(const u16* __restrict__ sa,
                                                  const u16* __restrict__ hnt,
                                                  const u16* __restrict__ Wih,
                                                  const u16* __restrict__ Whh,
                                                  const u16* __restrict__ Wens,
                                                  const float* __restrict__ bih,
                                                  const float* __restrict__ bhh,
                                                  const float* __restrict__ bens,
                                                  float* __restrict__ gi,
                                                  float* __restrict__ gh,
                                                  float* __restrict__ dout, int t) {
    __shared__ char As[8192];
    __shared__ char Bs[8192];
    int z = blockIdx.z;
    int m0 = blockIdx.y * 64, n0 = blockIdx.x * 64;
    if (z == 2 && n0 >= 1280) return;
    const u16* Ap = (z == 1) ? hnt : sa;
    auto fa = [&](int r, int k) { return *(const uint4*)(Ap + r * 1024 + k); };
    if (z == 0) {
        auto fe = [&](int r, int n, float v) { gi[(size_t)r * 3072 + n] = v + bih[n]; };
        gemm_tile(As, Bs, fa, Wih, 1024, 1024, m0, n0, fe);
    } else if (z == 1) {
        auto fe = [&](int r, int n, float v) { gh[(size_t)r * 3072 + n] = v + bhh[n]; };
        gemm_tile(As, Bs, fa, Whh, 1024, 1024, m0, n0, fe);
    } else {
        float* op = dout + (size_t)t * OUTC + 3584;
        auto fe = [&](int r, int n, float v) { op[(size_t)r * OUTT + n] = v + bens[n]; };
        gemm_tile(As, Bs, fa, Wens, 1024, 1024, m0, n0, fe);
    }
}

__global__ void __launch_bounds__(256) k_gemm_hpq(const u16* __restrict__ dtb,
                                                  const float* __restrict__ obs,
                                                  const u16* __restrict__ Wp1t,
                                                  const u16* __restrict__ Wq1t,
                                                  const float* __restrict__ bp1,
                                                  const float* __restrict__ bq1,
                                                  u16* __restrict__ hp,
                                                  u16* __restrict__ hq, int t) {
    __shared__ char As[8192];
    __shared__ char Bs[8192];
    int z = blockIdx.z;
    int m0 = blockIdx.y * 64, n0 = blockIdx.x * 64;
    if (z == 0) {
        auto fa = [&](int r, int k) { return *(const uint4*)(dtb + r * 1024 + k); };
        auto fe = [&](int r, int n, float v) {
            v = eluf(v + bp1[n]);
            hp[r * 1024 + n] = f2bf(v);
        };
        gemm_tile(As, Bs, fa, Wp1t, 1024, 1024, m0, n0, fe);
    } else {
        auto fa = [&](int r, int k) {
            if (k < 1024) return *(const uint4*)(dtb + r * 1024 + k);
            const float* q = obs + (size_t)r * (TT * EE) + (size_t)t * EE + (k - 1024);
            float4 f0 = *(const float4*)q, f1 = *(const float4*)(q + 4);
            union { u16 u[8]; uint4 v; } x;
            x.u[0] = f2bf(f0.x); x.u[1] = f2bf(f0.y); x.u[2] = f2bf(f0.z); x.u[3] = f2bf(f0.w);
            x.u[4] = f2bf(f1.x); x.u[5] = f2bf(f1.y); x.u[6] = f2bf(f1.z); x.u[7] = f2bf(f1.w);
            return x.v;
        };
        auto fe = [&](int r, int n, float v) {
            v = eluf(v + bq1[n]);
            hq[r * 1024 + n] = f2bf(v);
        };
        gemm_tile(As, Bs, fa, Wq1t, 2048, 2048, m0, n0, fe);
    }
}

__global__ void __launch_bounds__(256) k_gemm_pq(const u16* __restrict__ hp,
                                                 const u16* __restrict__ hq,
                                                 const u16* __restrict__ Wp2t,
                                                 const u16* __restrict__ Wq2t,
                                                 const float* __restrict__ bp2,
                                                 const float* __restrict__ bq2,
                                                 float* __restrict__ pout,
                                                 float* __restrict__ qout) {
    __shared__ char As[8192];
    __shared__ char Bs[8192];
    int z = blockIdx.z;
    int m0 = blockIdx.y * 64, n0 = blockIdx.x * 64;
    const u16* Ap = z ? hq : hp;
    const u16* Bp = z ? Wq2t : Wp2t;
    const float* bb = z ? bq2 : bp2;
    float* op = z ? qout : pout;
    auto fa = [&](int r, int k) { return *(const uint4*)(Ap + r * 1024 + k); };
    auto fe = [&](int r, int n, float v) { op[r * 512 + n] = v + bb[n]; };
    gemm_tile(As, Bs, fa, Bp, 1024, 1024, m0, n0, fe);
}

// ---------------- host ----------------
extern "C" void kernel_launch(void* const* d_in, const int* in_sizes, int n_in,
                              void* d_out, int out_size, void* d_ws, size_t ws_size,
                              hipStream_t stream) {
    const float* obs = (const float*)d_in[1];
    const float* action = (const float*)d_in[2];
    const float* nonterms = (const float*)d_in[3];
    const float* init_deter = (const float*)d_in[4];
    const float* init_stoch = (const float*)d_in[5];
    const float* noise_p = (const float*)d_in[6];
    const float* noise_q = (const float*)d_in[7];
    const float* W_embed = (const float*)d_in[8];
    const float* b_embed = (const float*)d_in[9];
    const float* W_ens = (const float*)d_in[10];
    const float* b_ens = (const float*)d_in[11];
    const float* W_ih = (const float*)d_in[12];
    const float* W_hh = (const float*)d_in[13];
    const float* b_ih = (const float*)d_in[14];
    const float* b_hh = (const float*)d_in[15];
    const float* Wp1 = (const float*)d_in[16];
    const float* bp1 = (const float*)d_in[17];
    const float* Wp2 = (const float*)d_in[18];
    const float* bp2 = (const float*)d_in[19];
    const float* Wq1 = (const float*)d_in[20];
    const float* bq1 = (const float*)d_in[21];
    const float* Wq2 = (const float*)d_in[22];
    const float* bq2 = (const float*)d_in[23];
    float* out = (float*)d_out;

    char* ws = (char*)d_ws;
    size_t off = 0;
    auto alloc = [&](size_t bytes) {
        void* p = ws + off;
        off += (bytes + 255) & ~(size_t)255;
        return p;
    };
    u16* Wembed_t = (u16*)alloc(1024 * 320 * 2);
    u16* Wih_b = (u16*)alloc(3072 * 1024 * 2);
    u16* Whh_b = (u16*)alloc(3072 * 1024 * 2);
    u16* Wens_t = (u16*)alloc(1280 * 1024 * 2);
    u16* Wp1_t = (u16*)alloc(1024 * 1024 * 2);
    u16* Wp2_t = (u16*)alloc(512 * 1024 * 2);
    u16* Wq1_t = (u16*)alloc((size_t)1024 * 2048 * 2);
    u16* Wq2_t = (u16*)alloc(512 * 1024 * 2);
    u16* x_embed = (u16*)alloc(256 * 320 * 2);
    u16* h_nt = (u16*)alloc(256 * 1024 * 2);
    u16* sa = (u16*)alloc(256 * 1024 * 2);
    float* deter = (float*)alloc(256 * 1024 * 4);
    u16* deter_b = (u16*)alloc(256 * 1024 * 2);
    float* gi = (float*)alloc((size_t)256 * 3072 * 4);
    float* gh = (float*)alloc((size_t)256 * 3072 * 4);
    u16* hp = (u16*)alloc(256 * 1024 * 2);
    u16* hq = (u16*)alloc(256 * 1024 * 2);
    float* pout = (float*)alloc(256 * 512 * 4);
    float* qout = (float*)alloc(256 * 512 * 4);
    (void)ws_size;

    // weights: cast / transpose to bf16 [N][K]
    {
        int tot = 1024 * 320;
        k_transpose<<<(tot + 255) / 256, 256, 0, stream>>>(W_embed, Wembed_t, 288, 1024, 320, tot);
        int nc = 3072 * 1024;
        k_cast<<<(nc + 255) / 256, 256, 0, stream>>>(W_ih, Wih_b, nc);
        k_cast<<<(nc + 255) / 256, 256, 0, stream>>>(W_hh, Whh_b, nc);
        tot = 5 * 256 * 1024;
        k_transpose<<<(tot + 255) / 256, 256, 0, stream>>>(W_ens, Wens_t, 1024, 256, 1024, tot);
        tot = 1024 * 1024;
        k_transpose<<<(tot + 255) / 256, 256, 0, stream>>>(Wp1, Wp1_t, 1024, 1024, 1024, tot);
        tot = 512 * 1024;
        k_transpose<<<(tot + 255) / 256, 256, 0, stream>>>(Wp2, Wp2_t, 1024, 512, 1024, tot);
        tot = 1024 * 2048;
        k_transpose<<<(tot + 255) / 256, 256, 0, stream>>>(Wq1, Wq1_t, 2048, 1024, 2048, tot);
        tot = 512 * 1024;
        k_transpose<<<(tot + 255) / 256, 256, 0, stream>>>(Wq2, Wq2_t, 1024, 512, 1024, tot);
    }

    k_prep0<<<1024, 256, 0, stream>>>(init_deter, init_stoch, action, nonterms,
                                      deter, h_nt, x_embed);

    for (int t = 0; t < TM1; t++) {
        k_gemm_sa<<<dim3(16, 4), 256, 0, stream>>>(x_embed, Wembed_t, b_embed, sa);
        k_gemm_big<<<dim3(48, 4, 3), 256, 0, stream>>>(sa, h_nt, Wih_b, Whh_b, Wens_t,
                                                       b_ih, b_hh, b_ens, gi, gh, out, t);
        k_gru<<<1024, 256, 0, stream>>>(gi, gh, deter, nonterms, t, deter_b, out);
        k_gemm_hpq<<<dim3(16, 4, 2), 256, 0, stream>>>(deter_b, obs, Wp1_t, Wq1_t,
                                                       bp1, bq1, hp, hq, t);
        k_gemm_pq<<<dim3(8, 4, 2), 256, 0, stream>>>(hp, hq, Wp2_t, Wq2_t, bp2, bq2,
                                                     pout, qout);
        k_dist<<<1024, 256, 0, stream>>>(pout, qout, noise_p, noise_q, t, deter,
                                         action, nonterms, out, x_embed, h_nt);
    }
}